// Round 2
// baseline (16472.897 us; speedup 1.0000x reference)
//
#include <hip/hip_runtime.h>
#include <hip/hip_bf16.h>
#include <stdint.h>

using bf16 = __hip_bfloat16;
typedef __attribute__((ext_vector_type(8))) short short8;
typedef __attribute__((ext_vector_type(4))) float f32x4;

#define NB   32
#define LSQ  128
#define TDEC 63
#define HD   1024
#define ED   512
#define VOUT 32000

static __device__ __forceinline__ unsigned short bits_of(bf16 b) {
  return *(unsigned short*)&b;
}

// ---------------- conversion / gather kernels ----------------
__global__ void f2b4(const float* __restrict__ s, bf16* __restrict__ d, long n4) {
  long i = blockIdx.x * (long)blockDim.x + threadIdx.x;
  long st = (long)gridDim.x * blockDim.x;
  for (; i < n4; i += st) {
    float4 v = ((const float4*)s)[i];
    bf16 b0 = __float2bfloat16(v.x), b1 = __float2bfloat16(v.y);
    bf16 b2 = __float2bfloat16(v.z), b3 = __float2bfloat16(v.w);
    ushort4 o = { bits_of(b0), bits_of(b1), bits_of(b2), bits_of(b3) };
    ((ushort4*)d)[i] = o;
  }
}

__global__ void f2b_sub(const float* __restrict__ s, bf16* __restrict__ d,
                        int ld, int col0, int cols, int total) {
  for (int i = blockIdx.x * blockDim.x + threadIdx.x; i < total;
       i += gridDim.x * blockDim.x) {
    int r = i / cols, c = i - r * cols;
    d[i] = __float2bfloat16(s[(long)r * ld + col0 + c]);
  }
}

// out row r = t*32 + n ; id = ids[n*L + t]
__global__ void gather_emb(const int* __restrict__ ids, int L,
                           const float* __restrict__ table, bf16* __restrict__ out) {
  int r = blockIdx.x;
  int t = r >> 5, n = r & 31;
  long id = ids[n * L + t];
  const float* srcp = table + id * (long)ED;
  bf16* dst = out + (long)r * ED;
  for (int c = threadIdx.x; c < ED; c += blockDim.x)
    dst[c] = __float2bfloat16(srcp[c]);
}

__global__ void zero_k(float* p, int n) {
  int i = blockIdx.x * blockDim.x + threadIdx.x;
  if (i < n) p[i] = 0.f;
}

// ---------------- bf16 GEMM: C[m,n] = sum_k A[m,k]*B[n,k] + bias[n] ----------------
// A: (Mpad,K) bf16 row-major; B: (N,K) bf16 row-major; C fp32 (M,N) (or remapped rows)
// remap=1: input row gr = t*32+n  -> out row n*63+t
__global__ __launch_bounds__(256) void gemm_bt(
    const bf16* __restrict__ A, const bf16* __restrict__ B,
    float* __restrict__ C, const float* __restrict__ bias,
    int M, int N, int K, int remap)
{
  __shared__ bf16 As[128 * 64];
  __shared__ bf16 Bs[128 * 64];
  int mt = blockIdx.x, nt = blockIdx.y;
  int tid = threadIdx.x;
  int wave = tid >> 6, lane = tid & 63;
  int wr = wave & 1, wc = wave >> 1;
  f32x4 acc[4][4] = {};
  const bf16* Ab = A + (size_t)mt * 128 * K;
  const bf16* Bb = B + (size_t)nt * 128 * K;
  int lrow = tid >> 3;            // 0..31
  int lk = (tid & 7) * 8;         // 0..56
  int row16 = lane & 15, kq = (lane >> 4) * 8;

  for (int k0 = 0; k0 < K; k0 += 64) {
    __syncthreads();
#pragma unroll
    for (int it = 0; it < 4; ++it) {
      int r = it * 32 + lrow;
      // LDS element offset for (row r, col lk) in row-major 128x64:
      // r*64 + lk = it*2048 + tid*8   (elements, NOT bytes)
      __builtin_amdgcn_global_load_lds(
          (const __attribute__((address_space(1))) void*)(Ab + (size_t)r * K + k0 + lk),
          (__attribute__((address_space(3))) void*)(As + it * 2048 + tid * 8), 16, 0, 0);
      __builtin_amdgcn_global_load_lds(
          (const __attribute__((address_space(1))) void*)(Bb + (size_t)r * K + k0 + lk),
          (__attribute__((address_space(3))) void*)(Bs + it * 2048 + tid * 8), 16, 0, 0);
    }
    __syncthreads();
#pragma unroll
    for (int kk = 0; kk < 64; kk += 32) {
      short8 af[4], bfr[4];
#pragma unroll
      for (int i = 0; i < 4; ++i)
        af[i] = *(const short8*)(As + (wr * 64 + i * 16 + row16) * 64 + kk + kq);
#pragma unroll
      for (int j = 0; j < 4; ++j)
        bfr[j] = *(const short8*)(Bs + (wc * 64 + j * 16 + row16) * 64 + kk + kq);
#pragma unroll
      for (int i = 0; i < 4; ++i)
#pragma unroll
        for (int j = 0; j < 4; ++j)
          acc[i][j] = __builtin_amdgcn_mfma_f32_16x16x32_bf16(af[i], bfr[j], acc[i][j], 0, 0, 0);
    }
  }
  int quad = lane >> 4;
#pragma unroll
  for (int i = 0; i < 4; ++i) {
    int gr0 = mt * 128 + wr * 64 + i * 16;
#pragma unroll
    for (int j = 0; j < 4; ++j) {
      int gc = nt * 128 + wc * 64 + j * 16 + row16;
      float bv = bias ? bias[gc] : 0.f;
#pragma unroll
      for (int rg = 0; rg < 4; ++rg) {
        int gr = gr0 + quad * 4 + rg;
        if (gr < M) {
          long orow = remap ? ((long)(gr & 31) * TDEC + (gr >> 5)) : (long)gr;
          C[orow * N + gc] = acc[i][j][rg] + bv;
        }
      }
    }
  }
}

// ---------------- RNN cell: h_out[n,j] = tanh(ig[n,j]+bias[j] + x1.W1 + x2.W2) ----------------
// grid 128 blocks x 256 thr; block b covers j in [b*8, b*8+8), all n.
__global__ __launch_bounds__(256) void cell_step(
    const float* __restrict__ x1, const float* __restrict__ W1, int ld1, int off1,
    const float* __restrict__ x2, const float* __restrict__ W2, int ld2, int off2,
    const float* __restrict__ ig, const float* __restrict__ bias,
    float* __restrict__ hout, bf16* __restrict__ bout, int bld)
{
  __shared__ float xs[NB][260];
  int tid = threadIdx.x;
  int n = tid & 31, jl = tid >> 5;
  int j = blockIdx.x * 8 + jl;
  float acc = ig[n * HD + j] + bias[j];
  for (int pass = 0; pass < 2; ++pass) {
    const float* x = pass ? x2 : x1;
    if (!x) continue;
    const float* W = pass ? W2 : W1;
    int ld = pass ? ld2 : ld1;
    int off = pass ? off2 : off1;
    const float* wbase = W + (long)j * ld + off;
    for (int kc = 0; kc < HD; kc += 256) {
      __syncthreads();
      for (int idx = tid; idx < NB * 256; idx += 256) {
        int nn = idx >> 8, cc = idx & 255;
        xs[nn][cc] = x[nn * HD + kc + cc];
      }
      __syncthreads();
      const float* wrow = wbase + kc;
#pragma unroll 8
      for (int kk = 0; kk < 256; kk += 4) {
        float4 wv = *(const float4*)(wrow + kk);
        float4 xv = *(const float4*)(&xs[n][kk]);
        acc += xv.x * wv.x + xv.y * wv.y + xv.z * wv.z + xv.w * wv.w;
      }
    }
  }
  float hv = tanhf(acc);
  hout[n * HD + j] = hv;
  if (bout) bout[(long)n * bld + j] = __float2bfloat16(hv);
}

// ---------------- decoder attention: one block per batch element ----------------
__global__ __launch_bounds__(256) void dec_attn(
    const float* __restrict__ hp, const float* __restrict__ energy,
    const float* __restrict__ enc_hs, const int* __restrict__ src,
    float* __restrict__ ctx, bf16* __restrict__ zctx)
{
  __shared__ float hn[HD];
  __shared__ float wl[LSQ];
  int n = blockIdx.x, tid = threadIdx.x;
  for (int c = tid; c < HD; c += 256) hn[c] = hp[n * HD + c];
  __syncthreads();
  int wave = tid >> 6, lane = tid & 63;
  for (int li = 0; li < 32; ++li) {
    int l = wave * 32 + li;
    const float* er = energy + ((long)l * NB + n) * HD;
    float p = 0.f;
    for (int c = lane; c < HD; c += 64) p += er[c] * hn[c];
    for (int o = 32; o >= 1; o >>= 1) p += __shfl_xor(p, o);
    if (lane == 0) wl[l] = (src[n * LSQ + l] == 0) ? -1e9f : p;
  }
  __syncthreads();
  if (wave == 0) {
    float a = wl[lane], b = wl[lane + 64];
    float m = fmaxf(a, b);
    for (int o = 32; o >= 1; o >>= 1) m = fmaxf(m, __shfl_xor(m, o));
    float ea = __expf(a - m), eb = __expf(b - m);
    float s = ea + eb;
    for (int o = 32; o >= 1; o >>= 1) s += __shfl_xor(s, o);
    float inv = 1.f / s;
    wl[lane] = ea * inv; wl[lane + 64] = eb * inv;
  }
  __syncthreads();
  for (int c = tid; c < HD; c += 256) {
    float a2 = 0.f;
#pragma unroll 4
    for (int l = 0; l < LSQ; ++l) a2 += wl[l] * enc_hs[((long)l * NB + n) * HD + c];
    ctx[n * HD + c] = a2;
    zctx[(long)n * 2048 + c] = __float2bfloat16(a2);
  }
}

// ---------------- log-softmax: per-row logsumexp then subtract ----------------
__global__ __launch_bounds__(256) void lse_k(const float* __restrict__ out, float* __restrict__ stats) {
  int row = blockIdx.x;
  const float* p = out + (long)row * VOUT;
  float m = -1e30f, s = 0.f;
  for (int c = threadIdx.x; c < VOUT; c += 256) {
    float x = p[c];
    if (x > m) { s = s * __expf(m - x) + 1.f; m = x; }
    else s += __expf(x - m);
  }
  __shared__ float sm[256], ss[256];
  sm[threadIdx.x] = m; ss[threadIdx.x] = s;
  __syncthreads();
  for (int o = 128; o > 0; o >>= 1) {
    if (threadIdx.x < o) {
      float m1 = sm[threadIdx.x], s1 = ss[threadIdx.x];
      float m2 = sm[threadIdx.x + o], s2 = ss[threadIdx.x + o];
      float M = fmaxf(m1, m2);
      ss[threadIdx.x] = s1 * __expf(m1 - M) + s2 * __expf(m2 - M);
      sm[threadIdx.x] = M;
    }
    __syncthreads();
  }
  if (threadIdx.x == 0) stats[row] = sm[0] + __logf(ss[0]);
}

__global__ __launch_bounds__(256) void apply_lse(float* __restrict__ out, const float* __restrict__ stats) {
  int row = blockIdx.x;
  float l = stats[row];
  float* p = out + (long)row * VOUT;
  for (int c = threadIdx.x; c < VOUT; c += 256) p[c] -= l;
}

// ---------------- host ----------------
extern "C" void kernel_launch(void* const* d_in, const int* in_sizes, int n_in,
                              void* d_out, int out_size, void* d_ws, size_t ws_size,
                              hipStream_t stream) {
  const int*   src      = (const int*)d_in[0];
  const int*   tgt      = (const int*)d_in[1];
  const float* enc_embed= (const float*)d_in[2];
  const float* enc_Wih  = (const float*)d_in[3];
  const float* enc_bih  = (const float*)d_in[4];
  const float* enc_Whh  = (const float*)d_in[5];
  const float* enc_bhh  = (const float*)d_in[6];
  const float* dec_embed= (const float*)d_in[7];
  const float* attn_W   = (const float*)d_in[8];
  const float* attn_b   = (const float*)d_in[9];
  const float* dec_Wih  = (const float*)d_in[10];
  const float* dec_bih  = (const float*)d_in[11];
  const float* dec_Whh  = (const float*)d_in[12];
  const float* dec_bhh  = (const float*)d_in[13];
  const float* h2o_W    = (const float*)d_in[14];
  const float* h2o_b    = (const float*)d_in[15];
  float* out = (float*)d_out;

  char* ws = (char*)d_ws;
  size_t off = 0;
  auto alloc = [&](size_t bytes) { char* p = ws + off; off += (bytes + 255) & ~(size_t)255; return p; };
  bf16*  h2oW_b = (bf16*)alloc((size_t)VOUT * 2048 * 2);     // 131 MB
  bf16*  WihE_b = (bf16*)alloc((size_t)HD * ED * 2);
  bf16*  attnW_b= (bf16*)alloc((size_t)HD * HD * 2);
  bf16*  Wde_b  = (bf16*)alloc((size_t)HD * ED * 2);
  bf16*  embS_b = (bf16*)alloc((size_t)4096 * ED * 2);
  bf16*  embT_b = (bf16*)alloc((size_t)2048 * ED * 2);
  bf16*  Zb     = (bf16*)alloc((size_t)2048 * 2048 * 2);
  float* ig_enc = (float*)alloc((size_t)4096 * HD * 4);
  float* enc_hs_f=(float*)alloc((size_t)4096 * HD * 4);
  bf16*  enc_hs_b=(bf16*)alloc((size_t)4096 * HD * 2);
  float* ig_dec = (float*)alloc((size_t)2048 * HD * 4);
  float* dec_h  = (float*)alloc((size_t)2016 * HD * 4);
  float* ctx    = (float*)alloc((size_t)NB * HD * 4);
  float* h0     = (float*)alloc((size_t)NB * HD * 4);
  float* stats  = (float*)alloc((size_t)2016 * 4);
  // energy aliases ig_enc: ig_enc is dead after the encoder recurrence,
  // energy is produced strictly after it. Saves 16 MB peak ws.
  float* energy = ig_enc;
  (void)ws_size; (void)in_sizes; (void)n_in; (void)out_size;

  // weight conversions + embedding gathers
  f2b4<<<4096, 256, 0, stream>>>(h2o_W, h2oW_b, (long)VOUT * 2048 / 4);
  f2b4<<<512, 256, 0, stream>>>(enc_Wih, WihE_b, (long)HD * ED / 4);
  f2b4<<<1024, 256, 0, stream>>>(attn_W, attnW_b, (long)HD * HD / 4);
  f2b_sub<<<1024, 256, 0, stream>>>(dec_Wih, Wde_b, ED + HD, 0, ED, HD * ED);
  gather_emb<<<4096, 128, 0, stream>>>(src, LSQ, enc_embed, embS_b);
  gather_emb<<<2016, 128, 0, stream>>>(tgt, 64, dec_embed, embT_b);
  zero_k<<<128, 256, 0, stream>>>(h0, NB * HD);

  // encoder input gates: (4096,512)x(1024,512)^T
  gemm_bt<<<dim3(32, 8), 256, 0, stream>>>(embS_b, WihE_b, ig_enc, enc_bih, 4096, HD, ED, 0);

  // encoder recurrence
  for (int t = 0; t < LSQ; ++t) {
    const float* hp = t ? enc_hs_f + (long)(t - 1) * NB * HD : h0;
    cell_step<<<128, 256, 0, stream>>>(hp, enc_Whh, HD, 0,
                                       nullptr, nullptr, 0, 0,
                                       ig_enc + (long)t * NB * HD, enc_bhh,
                                       enc_hs_f + (long)t * NB * HD,
                                       enc_hs_b + (long)t * NB * HD, HD);
  }

  // decoder input gates from embeddings: (2016,512)x(1024,512)^T
  // (before energy GEMM because energy aliases ig_enc? no — ig_dec is separate;
  //  order kept: ig_dec GEMM reads embT_b only, writes ig_dec only)
  gemm_bt<<<dim3(16, 8), 256, 0, stream>>>(embT_b, Wde_b, ig_dec, dec_bih, 2016, HD, ED, 0);

  // energy = enc_hs @ attn_W.T + attn_b   (overwrites ig_enc — now dead)
  gemm_bt<<<dim3(32, 8), 256, 0, stream>>>(enc_hs_b, attnW_b, energy, attn_b, 4096, HD, HD, 0);

  // decoder recurrence
  for (int t = 0; t < TDEC; ++t) {
    const float* hp = t ? dec_h + (long)(t - 1) * NB * HD
                        : enc_hs_f + (long)(LSQ - 1) * NB * HD;
    dec_attn<<<32, 256, 0, stream>>>(hp, energy, enc_hs_f, src, ctx,
                                     Zb + (long)t * NB * 2048 + HD);
    cell_step<<<128, 256, 0, stream>>>(ctx, dec_Wih, ED + HD, ED,
                                       hp, dec_Whh, HD, 0,
                                       ig_dec + (long)t * NB * HD, dec_bhh,
                                       dec_h + (long)t * NB * HD,
                                       Zb + (long)t * NB * 2048, 2048);
  }

  // big output projection: (2016,2048) x (32000,2048)^T -> out rows n*63+t
  gemm_bt<<<dim3(16, 250), 256, 0, stream>>>(Zb, h2oW_b, out, h2o_b, 2016, VOUT, 2048, 1);

  // log-softmax over vocab
  lse_k<<<2016, 256, 0, stream>>>(out, stats);
  apply_lse<<<2016, 256, 0, stream>>>(out, stats);
}